// Round 7
// baseline (493.099 us; speedup 1.0000x reference)
//
#include <hip/hip_runtime.h>

// GAT 3-layer on MI355X — bf16/MFMA pipeline.
//   CSR build: hist -> scan (cursor-init fused) -> bucket-partition -> scatter
//   prep: weights -> bf16 transposed
//   h0 = bf16(x @ lin_w + lin_b)   [coalesced fp32 staging -> LDS bf16 -> MFMA]
//   per layer: h' = h @ w (MFMA, attn dots fused); gather-aggregate (bf16 rows)
//   final layer: bias + L2 row normalize -> fp32 d_out.
// R6: gemm_pre restructured — R5 counters showed the per-lane row-major x
// reads are transaction-bound (64 scattered 16B reqs/instr), not latency
// bound. Stage the 64x256 tile coalesced into LDS (bf16, +8 pad), ds_read
// fragments. cursor_init folded into scan3.

constexpr float NEG_SLOPE = 0.2f;
#define BKT_SHIFT 9                // 512 nodes per bucket
#define BKT_N     512
#define PCHUNK    2048             // edges staged per partition block

typedef __attribute__((ext_vector_type(8))) short bf16x8;
typedef __attribute__((ext_vector_type(4))) float f32x4;

__device__ inline ushort f2bf(float x) {
    union { float f; uint u; } v; v.f = x;
    return (ushort)((v.u + 0x7FFFu + ((v.u >> 16) & 1u)) >> 16);
}
__device__ inline void bf2f(uint u, float& lo, float& hi) {
    union { uint u; float f; } a, b;
    a.u = u << 16; b.u = u & 0xFFFF0000u;
    lo = a.f; hi = b.f;
}
__device__ inline uint pk(float a, float b) {
    return (uint)f2bf(a) | ((uint)f2bf(b) << 16);
}

// ---------------- weight prep: bf16 transpose ---------------------------------
__global__ __launch_bounds__(256) void prep_w(
    const float* __restrict__ lw, const float* __restrict__ w1,
    const float* __restrict__ w2, const float* __restrict__ w3,
    ushort* __restrict__ lwT, ushort* __restrict__ w1T,
    ushort* __restrict__ w2T, ushort* __restrict__ w3T)
{
    const int i = blockIdx.x * 256 + threadIdx.x;
    if (i < 64 * 256) {                 // lwT[n][k] = lw[k][n], K=256
        const int nn = i >> 8, k = i & 255;
        lwT[i] = f2bf(lw[k * 64 + nn]);
    } else {
        const int j = i - 64 * 256;
        if (j < 4096) {                 // wT[n][k] = w[k][n], K=64
            const int nn = j >> 6, k = j & 63;
            w1T[j] = f2bf(w1[k * 64 + nn]);
            w2T[j] = f2bf(w2[k * 64 + nn]);
            w3T[j] = f2bf(w3[k * 64 + nn]);
        }
    }
}

// ---------------- GEMM1: h0 = bf16(x[M x 256] @ lin_w + lin_b) ----------------
// Block = 64 rows. Stage fp32 tile COALESCED (lane i reads base+i*16B),
// convert to bf16 into LDS [64][264] (pad 8 -> even bank spread), then
// per-wave MFMA from ds_read_b128 fragments. B = lwT bf16 [64][256] L1-hot.
__global__ __launch_bounds__(256) void gemm_pre(
    const float* __restrict__ x, const ushort* __restrict__ lwT,
    const float* __restrict__ bias, ushort* __restrict__ C, int M)
{
    __shared__ __align__(16) ushort As[64][264];
    __shared__ __align__(16) ushort ctile[4][16][64];
    const int tid = threadIdx.x;
    const int w = tid >> 6, lane = tid & 63;
    const int row0 = blockIdx.x * 64;

    // ---- coalesced staging: 64 rows x 256 cols fp32 -> bf16 LDS ----
    float4 pv[16];
    #pragma unroll
    for (int i = 0; i < 16; ++i) {
        const int li  = i * 256 + tid;      // 0..4095
        const int row = li >> 6;            // 0..63
        const int c4  = li & 63;            // float4 index in row
        pv[i] = (row0 + row < M)
              ? *(const float4*)(x + (size_t)(row0 + row) * 256 + c4 * 4)
              : make_float4(0.f, 0.f, 0.f, 0.f);
    }
    #pragma unroll
    for (int i = 0; i < 16; ++i) {
        const int li  = i * 256 + tid;
        const int row = li >> 6;
        const int c4  = li & 63;
        ushort4 o;
        o.x = f2bf(pv[i].x); o.y = f2bf(pv[i].y);
        o.z = f2bf(pv[i].z); o.w = f2bf(pv[i].w);
        *(ushort4*)(&As[row][c4 * 4]) = o;
    }
    __syncthreads();

    // ---- MFMA: wave w handles local rows w*16 .. w*16+15 ----
    const int c = lane & 15, q = lane >> 4;
    const int rw0 = row0 + w * 16;

    f32x4 acc[4];
    #pragma unroll
    for (int t = 0; t < 4; ++t) acc[t] = (f32x4){0.f, 0.f, 0.f, 0.f};

    #pragma unroll
    for (int s = 0; s < 8; ++s) {
        const bf16x8 af = *(const bf16x8*)(&As[w * 16 + c][q * 8 + s * 32]);
        #pragma unroll
        for (int t = 0; t < 4; ++t) {
            const bf16x8 bf = *(const bf16x8*)(lwT + (size_t)(t * 16 + c) * 256 + s * 32 + q * 8);
            acc[t] = __builtin_amdgcn_mfma_f32_16x16x32_bf16(af, bf, acc[t], 0, 0, 0);
        }
    }

    // bias + bf16 store via per-wave LDS transpose (C/D: row=q*4+reg, col=16t+c)
    #pragma unroll
    for (int t = 0; t < 4; ++t) {
        const float bv = bias[t * 16 + c];
        #pragma unroll
        for (int r = 0; r < 4; ++r)
            ctile[w][q * 4 + r][t * 16 + c] = f2bf(acc[t][r] + bv);
    }
    const int row = lane >> 2, eo = (lane & 3) * 16;
    if (rw0 + row < M) {
        const uint4 v0 = *(const uint4*)(&ctile[w][row][eo]);
        const uint4 v1 = *(const uint4*)(&ctile[w][row][eo + 8]);
        *(uint4*)(C + (size_t)(rw0 + row) * 64 + eo)     = v0;
        *(uint4*)(C + (size_t)(rw0 + row) * 64 + eo + 8) = v1;
    }
}

// ---------------- layer GEMM: C = A[M x 64] @ w, + attn dots ------------------
// A bf16 row-major, WT bf16 [n][k]. Emits C bf16 and hs/hd fp32 (pre-bias).
__global__ __launch_bounds__(256) void gemm_layer(
    const ushort* __restrict__ A, const ushort* __restrict__ WT,
    const float* __restrict__ a_s, const float* __restrict__ a_d,
    ushort* __restrict__ C, float* __restrict__ hs, float* __restrict__ hd, int M)
{
    __shared__ __align__(16) ushort ctile[4][16][64];
    const int tid = threadIdx.x;
    const int w = tid >> 6, lane = tid & 63;
    const int rw0 = (blockIdx.x * 4 + w) * 16;
    if (rw0 >= M) return;
    const int c = lane & 15, q = lane >> 4;

    const ushort* ap = A + (size_t)(rw0 + c) * 64 + q * 8;
    const bf16x8 a0 = *(const bf16x8*)(ap);
    const bf16x8 a1 = *(const bf16x8*)(ap + 32);

    f32x4 acc[4];
    #pragma unroll
    for (int t = 0; t < 4; ++t) {
        const ushort* bp = WT + (size_t)(t * 16 + c) * 64 + q * 8;
        const bf16x8 b0 = *(const bf16x8*)(bp);
        const bf16x8 b1 = *(const bf16x8*)(bp + 32);
        f32x4 a = (f32x4){0.f, 0.f, 0.f, 0.f};
        a = __builtin_amdgcn_mfma_f32_16x16x32_bf16(a0, b0, a, 0, 0, 0);
        a = __builtin_amdgcn_mfma_f32_16x16x32_bf16(a1, b1, a, 0, 0, 0);
        acc[t] = a;
    }

    // attn dots: hs[r] = sum_n C[r][n]*a_s[n]; lane holds cols {16t+c}
    float ps[4] = {0.f, 0.f, 0.f, 0.f}, pd[4] = {0.f, 0.f, 0.f, 0.f};
    #pragma unroll
    for (int t = 0; t < 4; ++t) {
        const float as = a_s[t * 16 + c], ad = a_d[t * 16 + c];
        #pragma unroll
        for (int r = 0; r < 4; ++r) {
            ps[r] = fmaf(acc[t][r], as, ps[r]);
            pd[r] = fmaf(acc[t][r], ad, pd[r]);
        }
    }
    #pragma unroll
    for (int r = 0; r < 4; ++r) {
        #pragma unroll
        for (int off = 1; off < 16; off <<= 1) {
            ps[r] += __shfl_xor(ps[r], off);
            pd[r] += __shfl_xor(pd[r], off);
        }
    }
    if (c == 0) {
        #pragma unroll
        for (int r = 0; r < 4; ++r) {
            hs[rw0 + q * 4 + r] = ps[r];
            hd[rw0 + q * 4 + r] = pd[r];
        }
    }

    // bf16 store via per-wave LDS transpose
    #pragma unroll
    for (int t = 0; t < 4; ++t)
        #pragma unroll
        for (int r = 0; r < 4; ++r)
            ctile[w][q * 4 + r][t * 16 + c] = f2bf(acc[t][r]);
    const int row = lane >> 2, eo = (lane & 3) * 16;
    const uint4 v0 = *(const uint4*)(&ctile[w][row][eo]);
    const uint4 v1 = *(const uint4*)(&ctile[w][row][eo + 8]);
    *(uint4*)(C + (size_t)(rw0 + row) * 64 + eo)     = v0;
    *(uint4*)(C + (size_t)(rw0 + row) * 64 + eo + 8) = v1;
}

// ---------------- CSR build --------------------------------------------------
__global__ __launch_bounds__(256) void edge_hist(
    const int* __restrict__ dst, int* __restrict__ cnt, int e)
{
    const int i = blockIdx.x * blockDim.x + threadIdx.x;
    if (i < e) atomicAdd(&cnt[dst[i]], 1);
}

__global__ __launch_bounds__(256) void scan1(
    const int* __restrict__ cnt, int* __restrict__ out,
    int* __restrict__ bsum, int n)
{
    __shared__ int wsum[4];
    const int tid  = threadIdx.x;
    const int lane = tid & 63;
    const int w    = tid >> 6;
    const int base = blockIdx.x * 1024;
    int vals[4];
    int tsum = 0;
    #pragma unroll
    for (int i = 0; i < 4; ++i) {
        const int idx = base + tid * 4 + i;
        vals[i] = (idx < n) ? cnt[idx] : 0;
        tsum += vals[i];
    }
    int x = tsum;
    #pragma unroll
    for (int off = 1; off < 64; off <<= 1) {
        const int y = __shfl_up(x, off);
        if (lane >= off) x += y;
    }
    if (lane == 63) wsum[w] = x;
    __syncthreads();
    int wofs = 0;
    for (int k = 0; k < w; ++k) wofs += wsum[k];
    int excl = wofs + x - tsum;
    #pragma unroll
    for (int i = 0; i < 4; ++i) {
        const int idx = base + tid * 4 + i;
        if (idx < n) out[idx] = excl;
        excl += vals[i];
    }
    if (tid == 255) bsum[blockIdx.x] = wofs + x;
}

__global__ __launch_bounds__(128) void scan2(int* __restrict__ b, int nb)
{
    __shared__ int wtot[2];
    const int tid = threadIdx.x;
    const int lane = tid & 63;
    const int w = tid >> 6;
    const int v = (tid < nb) ? b[tid] : 0;
    int x = v;
    #pragma unroll
    for (int off = 1; off < 64; off <<= 1) {
        const int y = __shfl_up(x, off);
        if (lane >= off) x += y;
    }
    if (lane == 63) wtot[w] = x;
    __syncthreads();
    const int add = (w == 1) ? wtot[0] : 0;
    if (tid < nb) b[tid] = add + x - v;
}

// adds block offsets; also emits bucket cursors (gcur[b] = offs[b*512])
__global__ __launch_bounds__(256) void scan3(
    int* __restrict__ out, const int* __restrict__ bsum,
    int* __restrict__ gcur, int n, int total)
{
    const int idx = blockIdx.x * blockDim.x + threadIdx.x;
    if (idx < n) {
        const int v = out[idx] + bsum[idx >> 10];
        out[idx] = v;
        if ((idx & (BKT_N - 1)) == 0) gcur[idx >> BKT_SHIFT] = v;
    }
    if (idx == 0) out[n] = total;
}

// Phase 1: bucket edges by dst>>9 into CSR-aligned regions, coalesced runs.
// 2-pass over the global chunk (2nd read is L2-hot) — no scratch spill.
__global__ __launch_bounds__(256) void edge_partition(
    const int* __restrict__ src, const int* __restrict__ dst,
    int* __restrict__ gcursor, int2* __restrict__ pairs, int e, int nb)
{
    __shared__ int2 stage[PCHUNK];
    __shared__ int lcnt[256];
    __shared__ int lstart[256];
    __shared__ int lfill[256];
    __shared__ int gbase[256];
    __shared__ int wsum[4];

    const int tid  = threadIdx.x;
    const int lane = tid & 63;
    const int w    = tid >> 6;
    const int base = blockIdx.x * PCHUNK;
    const int cnt_here = min(PCHUNK, e - base);

    lcnt[tid] = 0; lfill[tid] = 0;
    __syncthreads();

    // pass 1: bucket histogram
    for (int i = tid; i < cnt_here; i += 256)
        atomicAdd(&lcnt[dst[base + i] >> BKT_SHIFT], 1);
    __syncthreads();

    // exclusive scan of lcnt[256] -> lstart; reserve global runs
    const int v = lcnt[tid];
    int x = v;
    #pragma unroll
    for (int off = 1; off < 64; off <<= 1) {
        const int y = __shfl_up(x, off);
        if (lane >= off) x += y;
    }
    if (lane == 63) wsum[w] = x;
    __syncthreads();
    int carry = 0;
    for (int k = 0; k < w; ++k) carry += wsum[k];
    lstart[tid] = carry + x - v;
    if (tid < nb && v > 0) gbase[tid] = atomicAdd(&gcursor[tid], v);
    __syncthreads();

    // pass 2: re-read (L2-hot) and stage bucket-major in LDS
    for (int i = tid; i < cnt_here; i += 256) {
        int2 it; it.x = src[base + i]; it.y = dst[base + i];
        const int b = it.y >> BKT_SHIFT;
        const int p = lstart[b] + atomicAdd(&lfill[b], 1);
        stage[p] = it;
    }
    __syncthreads();

    // contiguous write-out per bucket run
    for (int s = tid; s < cnt_here; s += 256) {
        const int2 it = stage[s];
        const int b = it.y >> BKT_SHIFT;
        pairs[gbase[b] + (s - lstart[b])] = it;
    }
}

// Phase 2: one block per bucket; per-node cursors in LDS; writes confined
// to this block's contiguous ssrc region (single-XCD line merging).
__global__ __launch_bounds__(256) void bucket_scatter(
    const int2* __restrict__ pairs, const int* __restrict__ offs,
    int* __restrict__ ssrc, int n)
{
    __shared__ int pos[BKT_N];
    const int node0 = blockIdx.x << BKT_SHIFT;
    const int node1 = min(n, node0 + BKT_N);
    const int tid = threadIdx.x;
    for (int i = tid; i < node1 - node0; i += 256) pos[i] = offs[node0 + i];
    __syncthreads();
    const int e0 = offs[node0];
    const int e1 = offs[node1];
    for (int j = e0 + tid; j < e1; j += 256) {
        const int2 it = pairs[j];
        const int p = atomicAdd(&pos[it.y - node0], 1);
        ssrc[p] = it.x;
    }
}

// ---------------- gather aggregation (bf16 rows) -----------------------------
// One wave per node; 8 edge slots x 8 lanes (16 B = 8 bf16 per lane).
// MODE 0: +bias, ReLU -> bf16 out.  MODE 1: +bias, L2 normalize -> fp32 out.
template <int MODE>
__global__ __launch_bounds__(256) void gat_agg(
    const ushort* __restrict__ hp, const float* __restrict__ hs,
    const float* __restrict__ hd, const int* __restrict__ offs,
    const int* __restrict__ ssrc, const float* __restrict__ bias,
    void* __restrict__ outv, int n)
{
    const int wid  = (blockIdx.x * blockDim.x + threadIdx.x) >> 6;
    const int lane = threadIdx.x & 63;
    if (wid >= n) return;
    const int sub = lane >> 3;          // edge slot 0..7
    const int f0  = (lane & 7) * 8;     // feature offset (8 bf16)

    const float hdi = hd[wid];
    float den = 0.f;
    float acc[8] = {};

    if (sub == 0) {   // self-loop
        float e = hs[wid] + hdi;
        e = (e > 0.f) ? e : NEG_SLOPE * e;
        const float ex = __expf(e);
        const uint4 t = *(const uint4*)(hp + (size_t)wid * 64 + f0);
        float f[8];
        bf2f(t.x, f[0], f[1]); bf2f(t.y, f[2], f[3]);
        bf2f(t.z, f[4], f[5]); bf2f(t.w, f[6], f[7]);
        den = ex;
        #pragma unroll
        for (int i = 0; i < 8; ++i) acc[i] = ex * f[i];
    }

    const int start = offs[wid];
    const int end   = offs[wid + 1];
    #pragma unroll 2
    for (int j = start + sub; j < end; j += 8) {
        const int s = ssrc[j];
        float e2 = hs[s] + hdi;
        e2 = (e2 > 0.f) ? e2 : NEG_SLOPE * e2;
        const float ex2 = __expf(e2);
        const uint4 t = *(const uint4*)(hp + (size_t)s * 64 + f0);
        float f[8];
        bf2f(t.x, f[0], f[1]); bf2f(t.y, f[2], f[3]);
        bf2f(t.z, f[4], f[5]); bf2f(t.w, f[6], f[7]);
        den += ex2;
        #pragma unroll
        for (int i = 0; i < 8; ++i) acc[i] = fmaf(ex2, f[i], acc[i]);
    }

    // reduce the 8 edge slots (lanes with same f0)
    #pragma unroll
    for (int off = 8; off < 64; off <<= 1) {
        den += __shfl_xor(den, off);
        #pragma unroll
        for (int i = 0; i < 8; ++i) acc[i] += __shfl_xor(acc[i], off);
    }

    const float4 bv0 = *(const float4*)(bias + f0);
    const float4 bv1 = *(const float4*)(bias + f0 + 4);
    const float bb[8] = {bv0.x, bv0.y, bv0.z, bv0.w, bv1.x, bv1.y, bv1.z, bv1.w};
    const float inv = 1.f / (den + 1e-16f);
    float v[8];
    #pragma unroll
    for (int i = 0; i < 8; ++i) v[i] = acc[i] * inv + bb[i];

    if (MODE == 0) {
        #pragma unroll
        for (int i = 0; i < 8; ++i) v[i] = fmaxf(v[i], 0.f);
        if (sub == 0) {
            uint4 o;
            o.x = pk(v[0], v[1]); o.y = pk(v[2], v[3]);
            o.z = pk(v[4], v[5]); o.w = pk(v[6], v[7]);
            *(uint4*)((ushort*)outv + (size_t)wid * 64 + f0) = o;
        }
    } else {
        float sq = 0.f;
        #pragma unroll
        for (int i = 0; i < 8; ++i) sq += v[i] * v[i];
        #pragma unroll
        for (int off = 1; off < 8; off <<= 1) sq += __shfl_xor(sq, off);
        const float s = 1.f / fmaxf(sqrtf(sq), 1e-12f);
        if (sub == 0) {
            float* op = (float*)outv + (size_t)wid * 64 + f0;
            float4 o0, o1;
            o0.x = v[0] * s; o0.y = v[1] * s; o0.z = v[2] * s; o0.w = v[3] * s;
            o1.x = v[4] * s; o1.y = v[5] * s; o1.z = v[6] * s; o1.w = v[7] * s;
            *(float4*)(op)     = o0;
            *(float4*)(op + 4) = o1;
        }
    }
}

// ---------------- launch -----------------------------------------------------
extern "C" void kernel_launch(void* const* d_in, const int* in_sizes, int n_in,
                              void* d_out, int out_size, void* d_ws, size_t ws_size,
                              hipStream_t stream)
{
    const float* x     = (const float*)d_in[0];
    const int*   src   = (const int*)d_in[1];
    const int*   dst   = (const int*)d_in[2];
    const float* lin_w = (const float*)d_in[3];
    const float* lin_b = (const float*)d_in[4];
    const float* w1  = (const float*)d_in[5];
    const float* a1s = (const float*)d_in[6];
    const float* a1d = (const float*)d_in[7];
    const float* b1  = (const float*)d_in[8];
    const float* w2  = (const float*)d_in[9];
    const float* a2s = (const float*)d_in[10];
    const float* a2d = (const float*)d_in[11];
    const float* b2  = (const float*)d_in[12];
    const float* w3  = (const float*)d_in[13];
    const float* a3s = (const float*)d_in[14];
    const float* a3d = (const float*)d_in[15];
    const float* b3  = (const float*)d_in[16];

    const int n = in_sizes[0] / 256;   // 100000 nodes
    const int E = in_sizes[1];         // 1280000 edges
    const int nb = (n + BKT_N - 1) >> BKT_SHIFT;

    char* wsp = (char*)d_ws;
    auto alloc = [&](size_t bytes) -> void* {
        void* p = (void*)wsp;
        wsp += (bytes + 255) & ~(size_t)255;
        return p;
    };
    ushort* bufA = (ushort*)alloc((size_t)n * 64 * sizeof(ushort));   // bf16 h
    ushort* bufB = (ushort*)alloc((size_t)n * 64 * sizeof(ushort));   // bf16 h'
    float*  hs   = (float*)alloc((size_t)n * sizeof(float));
    float*  hd   = (float*)alloc((size_t)n * sizeof(float));
    int*    offs = (int*)alloc((size_t)(n + 1) * sizeof(int));
    int*    cnt  = (int*)alloc((size_t)n * sizeof(int));
    int*    bsum = (int*)alloc(1024 * sizeof(int));
    int*    gcur = (int*)alloc(256 * sizeof(int));
    int*    ssrc = (int*)alloc((size_t)E * sizeof(int));
    int2*   pairs = (int2*)alloc((size_t)E * sizeof(int2));
    ushort* lwT = (ushort*)alloc(64 * 256 * sizeof(ushort));
    ushort* w1T = (ushort*)alloc(64 * 64 * sizeof(ushort));
    ushort* w2T = (ushort*)alloc(64 * 64 * sizeof(ushort));
    ushort* w3T = (ushort*)alloc(64 * 64 * sizeof(ushort));

    const int edgeBlocks = (E + 255) / 256;
    const int nodeWaveBlocks = (n + 3) / 4;
    const int gemmBlocks = (n + 63) / 64;
    const int nScanBlocks = (n + 1023) / 1024;
    const int partBlocks = (E + PCHUNK - 1) / PCHUNK;

    // ---- weight prep + CSR build ----
    prep_w<<<(64 * 256 + 4096 + 255) / 256, 256, 0, stream>>>(
        lin_w, w1, w2, w3, lwT, w1T, w2T, w3T);
    hipMemsetAsync(cnt, 0, (size_t)n * sizeof(int), stream);
    edge_hist<<<edgeBlocks, 256, 0, stream>>>(dst, cnt, E);
    scan1<<<nScanBlocks, 256, 0, stream>>>(cnt, offs, bsum, n);
    scan2<<<1, 128, 0, stream>>>(bsum, nScanBlocks);
    scan3<<<(n + 255) / 256, 256, 0, stream>>>(offs, bsum, gcur, n, E);
    edge_partition<<<partBlocks, 256, 0, stream>>>(src, dst, gcur, pairs, E, nb);
    bucket_scatter<<<nb, 256, 0, stream>>>(pairs, offs, ssrc, n);

    // ---- h0 = bf16(x @ lin_w + lin_b) ----
    gemm_pre<<<gemmBlocks, 256, 0, stream>>>(x, lwT, lin_b, bufA, n);

    // ---- layer 1 ----
    gemm_layer<<<gemmBlocks, 256, 0, stream>>>(bufA, w1T, a1s, a1d, bufB, hs, hd, n);
    gat_agg<0><<<nodeWaveBlocks, 256, 0, stream>>>(bufB, hs, hd, offs, ssrc, b1, bufA, n);

    // ---- layer 2 ----
    gemm_layer<<<gemmBlocks, 256, 0, stream>>>(bufA, w2T, a2s, a2d, bufB, hs, hd, n);
    gat_agg<0><<<nodeWaveBlocks, 256, 0, stream>>>(bufB, hs, hd, offs, ssrc, b2, bufA, n);

    // ---- layer 3 + normalize -> d_out ----
    gemm_layer<<<gemmBlocks, 256, 0, stream>>>(bufA, w3T, a3s, a3d, bufB, hs, hd, n);
    gat_agg<1><<<nodeWaveBlocks, 256, 0, stream>>>(bufB, hs, hd, offs, ssrc, b3,
                                                   d_out, n);
}